// Round 1
// 425.724 us; speedup vs baseline: 1.0090x; 1.0090x over previous
//
#include <hip/hip_runtime.h>

#define DIN 256
#define H   128
#define DOUT 64

#define EPI_RELU 0
#define EPI_BN   1
#define EPI_NONE 2

#define BKT_SHIFT 7                 // 128 nodes per bucket
#define BKT_NODES 128
#define BKT_CAP   4096              // slots per bucket (mean 2048, sigma ~45)
#define CSR_CAP   4608              // BKT_CAP + 128*3 align slack + 16 tail pad

typedef __attribute__((ext_vector_type(8))) short bf16x8;
typedef __attribute__((ext_vector_type(4))) float f32x4;

__device__ inline unsigned short f2bf(float f) {
  union { float f; unsigned u; } v; v.f = f;
  unsigned u = v.u;
  u += 0x7FFFu + ((u >> 16) & 1u);   // round-to-nearest-even
  return (unsigned short)(u >> 16);
}
__device__ inline float bf2f(unsigned u16) {
  union { unsigned u; float f; } v; v.u = u16 << 16;
  return v.f;
}

// ---------------- stage 1: bucket edges by dst>>7 ----------------
#define FILL_TPB 1024
#define FILL_EPT 16
#define FILL_EPB (FILL_TPB * FILL_EPT)

__global__ __launch_bounds__(FILL_TPB) void bucket_fill(
    const int* __restrict__ src, const int* __restrict__ dst,
    int* __restrict__ bcur, unsigned* __restrict__ bedges,
    int nbkt, int e) {
  __shared__ int hist[1024];        // >= nbkt (782)
  int tid = threadIdx.x;
  int base = blockIdx.x * FILL_EPB;
  for (int i = tid; i < nbkt; i += FILL_TPB) hist[i] = 0;
  __syncthreads();

  int es[FILL_EPT], ed[FILL_EPT];
#pragma unroll
  for (int j = 0; j < FILL_EPT; ++j) {
    int i = base + j * FILL_TPB + tid;
    if (i < e) {
      es[j] = src[i];
      ed[j] = dst[i];
      atomicAdd(&hist[ed[j] >> BKT_SHIFT], 1);
    } else {
      es[j] = -1; ed[j] = 0;
    }
  }
  __syncthreads();
  for (int b = tid; b < nbkt; b += FILL_TPB) {
    int cnt = hist[b];
    hist[b] = cnt ? atomicAdd(&bcur[b], cnt) : 0;
  }
  __syncthreads();
#pragma unroll
  for (int j = 0; j < FILL_EPT; ++j) {
    if (es[j] >= 0) {
      int b = ed[j] >> BKT_SHIFT;
      int p = atomicAdd(&hist[b], 1);
      if (p < BKT_CAP)
        bedges[(size_t)b * BKT_CAP + p] =
            (unsigned)es[j] | ((unsigned)(ed[j] & (BKT_NODES - 1)) << 17);
    }
  }
}

// ---------------- stage 2: in-LDS counting sort per bucket -> aligned CSR ----
// Each node's src list start is aligned to 4 ints (16B) so the aggregation
// kernel can block-load src indices with aligned int4 loads. Alignment gaps
// and a 16-int bucket tail are zero-filled (src=0 is always a valid row;
// padded edges are weight-masked in agg).
__global__ __launch_bounds__(256) void bucket_sort(
    const int* __restrict__ bcur, const unsigned* __restrict__ bedges,
    int* __restrict__ csr, int2* __restrict__ rowdeg, int n) {
  __shared__ unsigned rec[BKT_CAP];
  __shared__ int srcs[CSR_CAP];
  __shared__ int hist[BKT_NODES];
  __shared__ int cursor[BKT_NODES];
  __shared__ int s_total;
  int tid = threadIdx.x;
  int b = blockIdx.x;
  int cnt = bcur[b];
  if (cnt > BKT_CAP) cnt = BKT_CAP;
  const unsigned* eb = bedges + (size_t)b * BKT_CAP;

  if (tid < BKT_NODES) hist[tid] = 0;
  __syncthreads();
  for (int i = tid; i < cnt; i += 256) {
    unsigned r = eb[i];
    rec[i] = r;
    atomicAdd(&hist[(r >> 17) & 127], 1);
  }
  __syncthreads();
  int myc = (tid < BKT_NODES) ? hist[tid] : 0;
  int myc4 = (myc + 3) & ~3;        // 16B-aligned row length
  if (tid < BKT_NODES) hist[tid] = myc4;
  __syncthreads();
#pragma unroll
  for (int off = 1; off < BKT_NODES; off <<= 1) {
    int v = 0;
    if (tid < BKT_NODES && tid >= off) v = hist[tid - off];
    __syncthreads();
    if (tid < BKT_NODES) hist[tid] += v;
    __syncthreads();
  }
  int start = 0;
  if (tid < BKT_NODES) {
    start = hist[tid] - myc4;
    cursor[tid] = start;
    int node = b * BKT_NODES + tid;
    if (node < n) rowdeg[node] = make_int2(b * CSR_CAP + start, myc);
    if (tid == BKT_NODES - 1) s_total = hist[tid];
  }
  __syncthreads();
  for (int i = tid; i < cnt; i += 256) {
    unsigned r = rec[i];
    int p = atomicAdd(&cursor[(r >> 17) & 127], 1);
    srcs[p] = (int)(r & 0x1FFFFu);
  }
  // zero alignment gaps (disjoint from scatter targets, no sync needed)
  if (tid < BKT_NODES) {
    for (int g = start + myc; g < start + myc4; ++g) srcs[g] = 0;
  }
  __syncthreads();
  int total = s_total;
  if (tid < 16 && total + tid < CSR_CAP) srcs[total + tid] = 0;  // tail pad
  __syncthreads();
  int tot16 = total + 16;
  if (tot16 > CSR_CAP) tot16 = CSR_CAP;
  for (int i = tid; i < tot16; i += 256)
    csr[(size_t)b * CSR_CAP + i] = srcs[i];
}

// ---------------- mean aggregation v2: 4 nodes/wave, uint4 gather -----------
// Lane (grp,c): grp = lane>>4 picks one of 4 nodes, c = lane&15 picks the
// 16B chunk of the 256B bf16 row. One wave-load fetches 4 full rows (1KB).
// Src indices come via 4 aligned int4 broadcast loads per 16-edge chunk —
// no LDS, no shuffles. Tail edges are weight-masked (src padding is 0).
__global__ __launch_bounds__(256) void agg_kernel(
    const unsigned* __restrict__ h, const int2* __restrict__ rowdeg,
    const int* __restrict__ csr, unsigned* __restrict__ mean, int n) {
  int wid = (blockIdx.x * 256 + threadIdx.x) >> 6;
  int lane = threadIdx.x & 63;
  int grp = lane >> 4;
  int c = lane & 15;
  int node = wid * 4 + grp;
  bool valid = node < n;
  if (!valid) node = 0;
  int2 rd = rowdeg[node];
  int beg = rd.x, d = rd.y;

  const uint4* hv = (const uint4*)h;
  float a[8];
#pragma unroll
  for (int k = 0; k < 8; ++k) a[k] = 0.f;

  for (int j0 = 0; j0 < d; j0 += 16) {
    int rem = d - j0;
    const int4* sp = (const int4*)(csr + beg + j0);   // 16B aligned
    int sv[16];
    *(int4*)&sv[0]  = sp[0];
    *(int4*)&sv[4]  = sp[1];
    *(int4*)&sv[8]  = sp[2];
    *(int4*)&sv[12] = sp[3];
#pragma unroll
    for (int jj = 0; jj < 16; ++jj) {
      float w = (jj < rem) ? 1.f : 0.f;
      uint4 v = hv[(unsigned)(sv[jj] * 16 + c)];
#pragma unroll
      for (int k = 0; k < 4; ++k) {
        unsigned u = ((const unsigned*)&v)[k];
        union { unsigned u; float f; } lo, hi;
        lo.u = u << 16;
        hi.u = u & 0xffff0000u;
        a[2 * k]     = fmaf(w, lo.f, a[2 * k]);
        a[2 * k + 1] = fmaf(w, hi.f, a[2 * k + 1]);
      }
    }
  }

  if (valid) {
    float invd = 1.f / (float)(d > 0 ? d : 1);
    uint4 o;
    o.x = (unsigned)f2bf(a[0] * invd) | ((unsigned)f2bf(a[1] * invd) << 16);
    o.y = (unsigned)f2bf(a[2] * invd) | ((unsigned)f2bf(a[3] * invd) << 16);
    o.z = (unsigned)f2bf(a[4] * invd) | ((unsigned)f2bf(a[5] * invd) << 16);
    o.w = (unsigned)f2bf(a[6] * invd) | ((unsigned)f2bf(a[7] * invd) << 16);
    ((uint4*)mean)[(unsigned)(node * 16 + c)] = o;
  }
}

// ---------------- weight preconvert: Wt[m][k] = bf16(W[k][m]) ----------------
__global__ __launch_bounds__(256) void prep_w(
    const float* __restrict__ w_in, const float* __restrict__ w_l1,
    const float* __restrict__ w_r1, const float* __restrict__ w_l2,
    const float* __restrict__ w_r2, const float* __restrict__ w_out,
    unsigned short* __restrict__ t_in, unsigned short* __restrict__ t_l1,
    unsigned short* __restrict__ t_r1, unsigned short* __restrict__ t_l2,
    unsigned short* __restrict__ t_r2, unsigned short* __restrict__ t_out) {
  int i = blockIdx.x * 256 + threadIdx.x;
  const float* s; unsigned short* d; int K, M, off;
  if (i < 32768)       { s = w_in;  d = t_in;  K = 256; M = 128; off = i; }
  else if (i < 49152)  { s = w_l1;  d = t_l1;  K = 128; M = 128; off = i - 32768; }
  else if (i < 65536)  { s = w_r1;  d = t_r1;  K = 128; M = 128; off = i - 49152; }
  else if (i < 81920)  { s = w_l2;  d = t_l2;  K = 128; M = 128; off = i - 65536; }
  else if (i < 98304)  { s = w_r2;  d = t_r2;  K = 128; M = 128; off = i - 81920; }
  else if (i < 106496) { s = w_out; d = t_out; K = 128; M = 64;  off = i - 98304; }
  else return;
  int m = off / K, k = off % K;
  d[off] = f2bf(s[(size_t)k * M + m]);
}

// ---------------- bf16 MFMA GEMM v3: wave-contiguous loads + swizzled LDS ----
// 64 rows/block, 256 thr = 4 waves (wave w owns rows w*16..+15). All global
// loads are 1KB-contiguous per wave-instruction (lane i -> base + i*16B).
// A and B tiles live in LDS with XOR swizzle on 16B chunks:
//   chunk' = (chunk + row) & 15  ->  every ds_read_b128 in the k-loop is
// exactly 2-way bank-aliased (free, m136), no padding (keeps b128 alignment).
template <int NPH, int KOFF2, int AKA, int AKW, int M, int EPI, bool AFP32, bool OUTF32>
__global__ __launch_bounds__(256) void gemm_mfma(
    const void* __restrict__ A1, const void* __restrict__ A2,
    const unsigned short* __restrict__ W1, const unsigned short* __restrict__ W2,
    const float* __restrict__ bias, const float* __restrict__ gamma,
    const float* __restrict__ beta, void* __restrict__ Cv, int n) {
  constexpr int NT = M / 16;
  __shared__ __align__(16) unsigned short As[64 * 128];   // 16 KB
  __shared__ __align__(16) unsigned short Bs[M * 128];    // 32/16 KB

  int tid = threadIdx.x, lane = tid & 63, wave = tid >> 6;
  int m16 = lane & 15, quad = lane >> 4;
  int row0 = blockIdx.x * 64;
  int sr = lane >> 4;          // row-in-group 0..3
  int sc = lane & 15;          // 16B chunk 0..15

  f32x4 acc[NT];
#pragma unroll
  for (int t = 0; t < NT; ++t) acc[t] = (f32x4){0.f, 0.f, 0.f, 0.f};

#pragma unroll
  for (int ph = 0; ph < NPH; ++ph) {
    const void* A_ = ph ? A2 : A1;
    const unsigned short* W = ph ? W2 : W1;
    const int koff = ph ? KOFF2 : 0;
    if (ph) __syncthreads();   // waves done reading previous tiles

    // ---- stage A tile: wave w rows w*16..+15 ----
    if constexpr (!AFP32) {
#pragma unroll
      for (int g = 0; g < 4; ++g) {
        int lr = wave * 16 + g * 4 + sr;
        int grow = row0 + lr; if (grow >= n) grow = n - 1;
        uint4 v = *(const uint4*)((const unsigned short*)A_ +
                                  (size_t)grow * AKA + koff + sc * 8);
        *(uint4*)&As[lr * 128 + ((sc + lr) & 15) * 8] = v;
      }
    } else {
      int sr2 = lane >> 5;     // 0..1
      int c32 = lane & 31;     // fp32 16B chunk 0..31
#pragma unroll
      for (int g = 0; g < 8; ++g) {
        int lr = wave * 16 + g * 2 + sr2;
        int grow = row0 + lr; if (grow >= n) grow = n - 1;
        float4 v = *(const float4*)((const float*)A_ +
                                    (size_t)grow * AKA + koff + c32 * 4);
        unsigned p0 = (unsigned)f2bf(v.x) | ((unsigned)f2bf(v.y) << 16);
        unsigned p1 = (unsigned)f2bf(v.z) | ((unsigned)f2bf(v.w) << 16);
        int ch = c32 >> 1;
        *(uint2*)&As[lr * 128 + ((ch + lr) & 15) * 8 + (c32 & 1) * 4] =
            make_uint2(p0, p1);
      }
    }
    // ---- stage B tile: wave w rows w*(M/4)..+M/4-1 ----
#pragma unroll
    for (int g = 0; g < M / 16; ++g) {
      int br = wave * (M / 4) + g * 4 + sr;
      uint4 v = *(const uint4*)(W + (size_t)br * AKW + koff + sc * 8);
      *(uint4*)&Bs[br * 128 + ((sc + br) & 15) * 8] = v;
    }
    __syncthreads();

    // ---- k-loop: LDS only ----
    int lrme = wave * 16 + m16;
#pragma unroll
    for (int kt = 0; kt < 4; ++kt) {
      int ch = kt * 4 + quad;
      bf16x8 a = *(const bf16x8*)&As[lrme * 128 + ((ch + lrme) & 15) * 8];
#pragma unroll
      for (int t = 0; t < NT; ++t) {
        int brow = t * 16 + m16;
        bf16x8 b = *(const bf16x8*)&Bs[brow * 128 + ((ch + brow) & 15) * 8];
        acc[t] = __builtin_amdgcn_mfma_f32_16x16x32_bf16(a, b, acc[t], 0, 0, 0);
      }
    }
  }

  const float inv_std = rsqrtf(1.f + 1e-5f);
#pragma unroll
  for (int t = 0; t < NT; ++t) {
    int col = t * 16 + m16;
    float bv = bias[col];
    float sc2 = 1.f, bt2 = 0.f;
    if constexpr (EPI == EPI_BN) {
      sc2 = gamma[col] * inv_std;
      bt2 = beta[col];
    }
#pragma unroll
    for (int r = 0; r < 4; ++r) {
      int row = row0 + wave * 16 + quad * 4 + r;
      if (row < n) {
        float v = acc[t][r] + bv;
        if constexpr (EPI == EPI_BN) v = fmaxf(v * sc2 + bt2, 0.f);
        else if constexpr (EPI == EPI_RELU) v = fmaxf(v, 0.f);
        if constexpr (OUTF32)
          ((float*)Cv)[(size_t)row * M + col] = v;
        else
          ((unsigned short*)Cv)[(size_t)row * M + col] = f2bf(v);
      }
    }
  }
}

extern "C" void kernel_launch(void* const* d_in, const int* in_sizes, int n_in,
                              void* d_out, int out_size, void* d_ws, size_t ws_size,
                              hipStream_t stream) {
  const float* x     = (const float*)d_in[0];
  const int*   ei    = (const int*)d_in[1];
  const float* w_in  = (const float*)d_in[2];
  const float* b_in  = (const float*)d_in[3];
  const float* w_l1  = (const float*)d_in[4];
  const float* b_l1  = (const float*)d_in[5];
  const float* w_r1  = (const float*)d_in[6];
  const float* g1    = (const float*)d_in[7];
  const float* be1   = (const float*)d_in[8];
  const float* w_l2  = (const float*)d_in[9];
  const float* b_l2  = (const float*)d_in[10];
  const float* w_r2  = (const float*)d_in[11];
  const float* g2    = (const float*)d_in[12];
  const float* be2   = (const float*)d_in[13];
  const float* w_out = (const float*)d_in[14];
  const float* b_out = (const float*)d_in[15];
  float* out = (float*)d_out;

  int N = in_sizes[0] / DIN;
  int E = in_sizes[1] / 2;
  const int* src = ei;       // edge_index[0]
  const int* dst = ei + E;   // edge_index[1]
  int nbkt = (N + BKT_NODES - 1) / BKT_NODES;   // 782

  char* ws = (char*)d_ws;
  size_t off = 0;
  auto alloc = [&](size_t bytes) -> char* {
    char* p = ws + off;
    off += (bytes + 255) & ~(size_t)255;
    return p;
  };
  unsigned short* buf0 = (unsigned short*)alloc((size_t)N * H * 2);  // h0 -> mean2
  unsigned short* buf1 = (unsigned short*)alloc((size_t)N * H * 2);  // mean1 -> h2
  unsigned short* buf2 = (unsigned short*)alloc((size_t)N * H * 2);  // h1
  int* bcur        = (int*)alloc((size_t)nbkt * 4);
  unsigned* bedges = (unsigned*)alloc((size_t)nbkt * BKT_CAP * 4);
  int* csr         = (int*)alloc((size_t)nbkt * CSR_CAP * 4);
  int2* rowdeg     = (int2*)alloc((size_t)N * 8);
  unsigned short* t_in  = (unsigned short*)alloc(32768 * 2);
  unsigned short* t_l1  = (unsigned short*)alloc(16384 * 2);
  unsigned short* t_r1  = (unsigned short*)alloc(16384 * 2);
  unsigned short* t_l2  = (unsigned short*)alloc(16384 * 2);
  unsigned short* t_r2  = (unsigned short*)alloc(16384 * 2);
  unsigned short* t_out = (unsigned short*)alloc(8192 * 2);
  (void)ws_size;

  // ---- CSR build: bucket -> in-LDS counting sort (16B-aligned rows) ----
  hipMemsetAsync(bcur, 0, (size_t)nbkt * 4, stream);
  bucket_fill<<<(E + FILL_EPB - 1) / FILL_EPB, FILL_TPB, 0, stream>>>(
      src, dst, bcur, bedges, nbkt, E);
  bucket_sort<<<nbkt, 256, 0, stream>>>(bcur, bedges, csr, rowdeg, N);
  prep_w<<<(106496 + 255) / 256, 256, 0, stream>>>(
      w_in, w_l1, w_r1, w_l2, w_r2, w_out, t_in, t_l1, t_r1, t_l2, t_r2, t_out);

  int gblocks = (N + 63) / 64;   // 1563
  int ablocks = (N + 15) / 16;   // 6250 (4 nodes per wave, 4 waves per block)

  // h0 = relu(x @ w_in + b_in)       [fp32 A, K=256 via 2 phases of same x]
  gemm_mfma<2, 128, 256, 256, 128, EPI_RELU, true, false><<<gblocks, 256, 0, stream>>>(
      x, x, t_in, t_in, b_in, nullptr, nullptr, buf0, N);
  // mean1
  agg_kernel<<<ablocks, 256, 0, stream>>>((const unsigned*)buf0, rowdeg,
                                          csr, (unsigned*)buf1, N);
  // h1 = relu(bn(mean1@w_l1 + h0@w_r1 + b_l1))
  gemm_mfma<2, 0, 128, 128, 128, EPI_BN, false, false><<<gblocks, 256, 0, stream>>>(
      buf1, buf0, t_l1, t_r1, b_l1, g1, be1, buf2, N);
  // mean2
  agg_kernel<<<ablocks, 256, 0, stream>>>((const unsigned*)buf2, rowdeg,
                                          csr, (unsigned*)buf0, N);
  // h2 = relu(bn(mean2@w_l2 + h1@w_r2 + b_l2))
  gemm_mfma<2, 0, 128, 128, 128, EPI_BN, false, false><<<gblocks, 256, 0, stream>>>(
      buf0, buf2, t_l2, t_r2, b_l2, g2, be2, buf1, N);
  // out = h2 @ w_out + b_out
  gemm_mfma<1, 0, 128, 128, 64, EPI_NONE, false, true><<<gblocks, 256, 0, stream>>>(
      buf1, buf1, t_out, t_out, b_out, nullptr, nullptr, out, N);
}

// Round 4
// 420.421 us; speedup vs baseline: 1.0217x; 1.0126x over previous
//
#include <hip/hip_runtime.h>

#define DIN 256
#define H   128
#define DOUT 64

#define EPI_RELU 0
#define EPI_BN   1
#define EPI_NONE 2

#define BKT_SHIFT 7                 // 128 nodes per bucket
#define BKT_NODES 128
#define BKT_CAP   4096              // slots per bucket (mean 2048, sigma ~45)
#define CSR_CAP   4608              // BKT_CAP + 128*3 align slack + 16 tail pad

typedef __attribute__((ext_vector_type(8))) short bf16x8;
typedef __attribute__((ext_vector_type(4))) float f32x4;

__device__ inline unsigned short f2bf(float f) {
  union { float f; unsigned u; } v; v.f = f;
  unsigned u = v.u;
  u += 0x7FFFu + ((u >> 16) & 1u);   // round-to-nearest-even
  return (unsigned short)(u >> 16);
}
__device__ inline float bf2f(unsigned u16) {
  union { unsigned u; float f; } v; v.u = u16 << 16;
  return v.f;
}
// pack two fp32 -> one u32 of 2x bf16, RNE via verified bit-twiddle
__device__ inline unsigned pk_bf16(float lo, float hi) {
  return (unsigned)f2bf(lo) | ((unsigned)f2bf(hi) << 16);
}

// async global->LDS DMA, 16B per lane; LDS dest = wave-uniform base + lane*16
__device__ inline void gload_lds16(const void* g, void* l) {
  __builtin_amdgcn_global_load_lds(
      (const __attribute__((address_space(1))) void*)g,
      (__attribute__((address_space(3))) void*)l, 16, 0, 0);
}

// ---------------- stage 1: bucket edges by dst>>7 ----------------
#define FILL_TPB 1024
#define FILL_EPT 16
#define FILL_EPB (FILL_TPB * FILL_EPT)

__global__ __launch_bounds__(FILL_TPB) void bucket_fill(
    const int* __restrict__ src, const int* __restrict__ dst,
    int* __restrict__ bcur, unsigned* __restrict__ bedges,
    int nbkt, int e) {
  __shared__ int hist[1024];        // >= nbkt (782)
  int tid = threadIdx.x;
  int base = blockIdx.x * FILL_EPB;
  for (int i = tid; i < nbkt; i += FILL_TPB) hist[i] = 0;
  __syncthreads();

  int es[FILL_EPT], ed[FILL_EPT];
#pragma unroll
  for (int j = 0; j < FILL_EPT; ++j) {
    int i = base + j * FILL_TPB + tid;
    if (i < e) {
      es[j] = src[i];
      ed[j] = dst[i];
      atomicAdd(&hist[ed[j] >> BKT_SHIFT], 1);
    } else {
      es[j] = -1; ed[j] = 0;
    }
  }
  __syncthreads();
  for (int b = tid; b < nbkt; b += FILL_TPB) {
    int cnt = hist[b];
    hist[b] = cnt ? atomicAdd(&bcur[b], cnt) : 0;
  }
  __syncthreads();
#pragma unroll
  for (int j = 0; j < FILL_EPT; ++j) {
    if (es[j] >= 0) {
      int b = ed[j] >> BKT_SHIFT;
      int p = atomicAdd(&hist[b], 1);
      if (p < BKT_CAP)
        bedges[(size_t)b * BKT_CAP + p] =
            (unsigned)es[j] | ((unsigned)(ed[j] & (BKT_NODES - 1)) << 17);
    }
  }
}

// ---------------- stage 2: in-LDS counting sort per bucket -> aligned CSR ----
__global__ __launch_bounds__(256) void bucket_sort(
    const int* __restrict__ bcur, const unsigned* __restrict__ bedges,
    int* __restrict__ csr, int2* __restrict__ rowdeg, int n) {
  __shared__ unsigned rec[BKT_CAP];
  __shared__ int srcs[CSR_CAP];
  __shared__ int hist[BKT_NODES];
  __shared__ int cursor[BKT_NODES];
  __shared__ int s_total;
  int tid = threadIdx.x;
  int b = blockIdx.x;
  int cnt = bcur[b];
  if (cnt > BKT_CAP) cnt = BKT_CAP;
  const unsigned* eb = bedges + (size_t)b * BKT_CAP;

  if (tid < BKT_NODES) hist[tid] = 0;
  __syncthreads();
  for (int i = tid; i < cnt; i += 256) {
    unsigned r = eb[i];
    rec[i] = r;
    atomicAdd(&hist[(r >> 17) & 127], 1);
  }
  __syncthreads();
  int myc = (tid < BKT_NODES) ? hist[tid] : 0;
  int myc4 = (myc + 3) & ~3;        // 16B-aligned row length
  if (tid < BKT_NODES) hist[tid] = myc4;
  __syncthreads();
#pragma unroll
  for (int off = 1; off < BKT_NODES; off <<= 1) {
    int v = 0;
    if (tid < BKT_NODES && tid >= off) v = hist[tid - off];
    __syncthreads();
    if (tid < BKT_NODES) hist[tid] += v;
    __syncthreads();
  }
  int start = 0;
  if (tid < BKT_NODES) {
    start = hist[tid] - myc4;
    cursor[tid] = start;
    int node = b * BKT_NODES + tid;
    if (node < n) rowdeg[node] = make_int2(b * CSR_CAP + start, myc);
    if (tid == BKT_NODES - 1) s_total = hist[tid];
  }
  __syncthreads();
  for (int i = tid; i < cnt; i += 256) {
    unsigned r = rec[i];
    int p = atomicAdd(&cursor[(r >> 17) & 127], 1);
    srcs[p] = (int)(r & 0x1FFFFu);
  }
  // zero alignment gaps (disjoint from scatter targets, no sync needed)
  if (tid < BKT_NODES) {
    for (int g = start + myc; g < start + myc4; ++g) srcs[g] = 0;
  }
  __syncthreads();
  int total = s_total;
  if (tid < 16 && total + tid < CSR_CAP) srcs[total + tid] = 0;  // tail pad
  __syncthreads();
  int tot16 = total + 16;
  if (tot16 > CSR_CAP) tot16 = CSR_CAP;
  for (int i = tid; i < tot16; i += 256)
    csr[(size_t)b * CSR_CAP + i] = srcs[i];
}

// ---------------- mean aggregation: 4 nodes/wave, uint4 gather --------------
__global__ __launch_bounds__(256) void agg_kernel(
    const unsigned* __restrict__ h, const int2* __restrict__ rowdeg,
    const int* __restrict__ csr, unsigned* __restrict__ mean, int n) {
  int wid = (blockIdx.x * 256 + threadIdx.x) >> 6;
  int lane = threadIdx.x & 63;
  int grp = lane >> 4;
  int c = lane & 15;
  int node = wid * 4 + grp;
  bool valid = node < n;
  if (!valid) node = 0;
  int2 rd = rowdeg[node];
  int beg = rd.x, d = rd.y;

  const uint4* hv = (const uint4*)h;
  float a[8];
#pragma unroll
  for (int k = 0; k < 8; ++k) a[k] = 0.f;

  for (int j0 = 0; j0 < d; j0 += 16) {
    int rem = d - j0;
    const int4* sp = (const int4*)(csr + beg + j0);   // 16B aligned
    int sv[16];
    *(int4*)&sv[0]  = sp[0];
    *(int4*)&sv[4]  = sp[1];
    *(int4*)&sv[8]  = sp[2];
    *(int4*)&sv[12] = sp[3];
#pragma unroll
    for (int jj = 0; jj < 16; ++jj) {
      float w = (jj < rem) ? 1.f : 0.f;
      uint4 v = hv[(unsigned)(sv[jj] * 16 + c)];
#pragma unroll
      for (int k = 0; k < 4; ++k) {
        unsigned u = ((const unsigned*)&v)[k];
        union { unsigned u; float f; } lo, hi;
        lo.u = u << 16;
        hi.u = u & 0xffff0000u;
        a[2 * k]     = fmaf(w, lo.f, a[2 * k]);
        a[2 * k + 1] = fmaf(w, hi.f, a[2 * k + 1]);
      }
    }
  }

  if (valid) {
    float invd = 1.f / (float)(d > 0 ? d : 1);
    uint4 o;
    o.x = pk_bf16(a[0] * invd, a[1] * invd);
    o.y = pk_bf16(a[2] * invd, a[3] * invd);
    o.z = pk_bf16(a[4] * invd, a[5] * invd);
    o.w = pk_bf16(a[6] * invd, a[7] * invd);
    ((uint4*)mean)[(unsigned)(node * 16 + c)] = o;
  }
}

// ---------------- weight preconvert: Wt[m][k] = bf16(W[k][m]) ----------------
__global__ __launch_bounds__(256) void prep_w(
    const float* __restrict__ w_in, const float* __restrict__ w_l1,
    const float* __restrict__ w_r1, const float* __restrict__ w_l2,
    const float* __restrict__ w_r2, const float* __restrict__ w_out,
    unsigned short* __restrict__ t_in, unsigned short* __restrict__ t_l1,
    unsigned short* __restrict__ t_r1, unsigned short* __restrict__ t_l2,
    unsigned short* __restrict__ t_r2, unsigned short* __restrict__ t_out) {
  int i = blockIdx.x * 256 + threadIdx.x;
  const float* s; unsigned short* d; int K, M, off;
  if (i < 32768)       { s = w_in;  d = t_in;  K = 256; M = 128; off = i; }
  else if (i < 49152)  { s = w_l1;  d = t_l1;  K = 128; M = 128; off = i - 32768; }
  else if (i < 65536)  { s = w_r1;  d = t_r1;  K = 128; M = 128; off = i - 49152; }
  else if (i < 81920)  { s = w_l2;  d = t_l2;  K = 128; M = 128; off = i - 65536; }
  else if (i < 98304)  { s = w_r2;  d = t_r2;  K = 128; M = 128; off = i - 81920; }
  else if (i < 106496) { s = w_out; d = t_out; K = 128; M = 64;  off = i - 98304; }
  else return;
  int m = off / K, k = off % K;
  d[off] = f2bf(s[(size_t)k * M + m]);
}

// ---------------- bf16 MFMA GEMM v4b: A straight to regs, B via DMA ---------
// 64 rows/block, 4 waves (wave w owns rows w*16..+15). Key structural facts:
//  * A fragments are wave-private -> never staged in LDS. Each lane loads its
//    own 4 bf16x8 fragments (row = wave*16 + (lane&15), chunk = kt*4 + lane>>4)
//    directly from global; per instruction the wave touches 16 rows x 64B
//    contiguous = sector-aligned segments.
//  * B tile staged via global_load_lds width=16 (no VGPR round-trip, no
//    ds_writes). LDS dest is linear; the XOR swizzle chunk'=(chunk+row)&15 is
//    applied by pre-swizzling the per-lane GLOBAL source address (m173):
//    lane(sr,sc) sources Wchunk(br,(sc-br)&15) so LDS(br,c)=Wchunk(br,(c-br)&15)
//    -- bit-identical to the verified v3 LDS image; read side unchanged.
//  * fp32->bf16 pack uses the verified f2bf bit-twiddle (RNE). The round-3
//    failure (absmax 0.134) is attributed to v_cvt_pk_bf16_f32 semantics.
//  * LDS = Bs only (32 KB @ M=128) -> 5 blocks/CU latency hiding.
template <int NPH, int KOFF2, int AKA, int AKW, int M, int EPI, bool AFP32, bool OUTF32>
__global__ __launch_bounds__(256) void gemm_mfma(
    const void* __restrict__ A1, const void* __restrict__ A2,
    const unsigned short* __restrict__ W1, const unsigned short* __restrict__ W2,
    const float* __restrict__ bias, const float* __restrict__ gamma,
    const float* __restrict__ beta, void* __restrict__ Cv, int n) {
  constexpr int NT = M / 16;
  __shared__ __align__(16) unsigned short Bs[M * 128];    // 32/16 KB

  int tid = threadIdx.x, lane = tid & 63, wave = tid >> 6;
  int m16 = lane & 15, quad = lane >> 4;
  int row0 = blockIdx.x * 64;
  int sr = lane >> 4;          // B-stage: row-in-group 0..3
  int sc = lane & 15;          // B-stage: dest 16B chunk 0..15

  int arow = row0 + wave * 16 + m16;
  if (arow >= n) arow = n - 1;

  f32x4 acc[NT];
#pragma unroll
  for (int t = 0; t < NT; ++t) acc[t] = (f32x4){0.f, 0.f, 0.f, 0.f};

#pragma unroll
  for (int ph = 0; ph < NPH; ++ph) {
    const void* A_ = ph ? A2 : A1;
    const unsigned short* W = ph ? W2 : W1;
    const int koff = ph ? KOFF2 : 0;
    if (ph) __syncthreads();   // all waves done reading previous B tile

    // ---- issue B tile DMA: wave w stages rows w*(M/4)..+(M/4-1) ----
#pragma unroll
    for (int g = 0; g < M / 16; ++g) {
      int br = wave * (M / 4) + g * 4 + sr;
      int cs = (sc - br) & 15;                    // pre-swizzled source chunk
      gload_lds16(W + (size_t)br * AKW + koff + cs * 8,
                  &Bs[(wave * (M / 4) + g * 4) * 128]);
    }

    // ---- A fragments straight to registers (overlaps B DMA latency) ----
    bf16x8 afrag[4];
    if constexpr (!AFP32) {
      const unsigned short* Ab =
          (const unsigned short*)A_ + (size_t)arow * AKA + koff;
#pragma unroll
      for (int kt = 0; kt < 4; ++kt)
        afrag[kt] = *(const bf16x8*)(Ab + (kt * 4 + quad) * 8);
    } else {
      const float* Af = (const float*)A_ + (size_t)arow * AKA + koff;
#pragma unroll
      for (int kt = 0; kt < 4; ++kt) {
        float4 v0 = *(const float4*)(Af + (kt * 4 + quad) * 8);
        float4 v1 = *(const float4*)(Af + (kt * 4 + quad) * 8 + 4);
        union { unsigned u[4]; bf16x8 v; } pk;
        pk.u[0] = pk_bf16(v0.x, v0.y);
        pk.u[1] = pk_bf16(v0.z, v0.w);
        pk.u[2] = pk_bf16(v1.x, v1.y);
        pk.u[3] = pk_bf16(v1.z, v1.w);
        afrag[kt] = pk.v;
      }
    }
    __syncthreads();   // drains B DMA (vmcnt) + A loads

    // ---- k-loop: B from LDS, A from regs ----
#pragma unroll
    for (int kt = 0; kt < 4; ++kt) {
      int ch = kt * 4 + quad;
#pragma unroll
      for (int t = 0; t < NT; ++t) {
        int brow = t * 16 + m16;
        bf16x8 b = *(const bf16x8*)&Bs[brow * 128 + ((ch + brow) & 15) * 8];
        acc[t] = __builtin_amdgcn_mfma_f32_16x16x32_bf16(afrag[kt], b, acc[t], 0, 0, 0);
      }
    }
  }

  const float inv_std = rsqrtf(1.f + 1e-5f);
#pragma unroll
  for (int t = 0; t < NT; ++t) {
    int col = t * 16 + m16;
    float bv = bias[col];
    float sc2 = 1.f, bt2 = 0.f;
    if constexpr (EPI == EPI_BN) {
      sc2 = gamma[col] * inv_std;
      bt2 = beta[col];
    }
#pragma unroll
    for (int r = 0; r < 4; ++r) {
      int row = row0 + wave * 16 + quad * 4 + r;
      if (row < n) {
        float v = acc[t][r] + bv;
        if constexpr (EPI == EPI_BN) v = fmaxf(v * sc2 + bt2, 0.f);
        else if constexpr (EPI == EPI_RELU) v = fmaxf(v, 0.f);
        if constexpr (OUTF32)
          ((float*)Cv)[(size_t)row * M + col] = v;
        else
          ((unsigned short*)Cv)[(size_t)row * M + col] = f2bf(v);
      }
    }
  }
}

extern "C" void kernel_launch(void* const* d_in, const int* in_sizes, int n_in,
                              void* d_out, int out_size, void* d_ws, size_t ws_size,
                              hipStream_t stream) {
  const float* x     = (const float*)d_in[0];
  const int*   ei    = (const int*)d_in[1];
  const float* w_in  = (const float*)d_in[2];
  const float* b_in  = (const float*)d_in[3];
  const float* w_l1  = (const float*)d_in[4];
  const float* b_l1  = (const float*)d_in[5];
  const float* w_r1  = (const float*)d_in[6];
  const float* g1    = (const float*)d_in[7];
  const float* be1   = (const float*)d_in[8];
  const float* w_l2  = (const float*)d_in[9];
  const float* b_l2  = (const float*)d_in[10];
  const float* w_r2  = (const float*)d_in[11];
  const float* g2    = (const float*)d_in[12];
  const float* be2   = (const float*)d_in[13];
  const float* w_out = (const float*)d_in[14];
  const float* b_out = (const float*)d_in[15];
  float* out = (float*)d_out;

  int N = in_sizes[0] / DIN;
  int E = in_sizes[1] / 2;
  const int* src = ei;       // edge_index[0]
  const int* dst = ei + E;   // edge_index[1]
  int nbkt = (N + BKT_NODES - 1) / BKT_NODES;   // 782

  char* ws = (char*)d_ws;
  size_t off = 0;
  auto alloc = [&](size_t bytes) -> char* {
    char* p = ws + off;
    off += (bytes + 255) & ~(size_t)255;
    return p;
  };
  unsigned short* buf0 = (unsigned short*)alloc((size_t)N * H * 2);  // h0 -> mean2
  unsigned short* buf1 = (unsigned short*)alloc((size_t)N * H * 2);  // mean1 -> h2
  unsigned short* buf2 = (unsigned short*)alloc((size_t)N * H * 2);  // h1
  int* bcur        = (int*)alloc((size_t)nbkt * 4);
  unsigned* bedges = (unsigned*)alloc((size_t)nbkt * BKT_CAP * 4);
  int* csr         = (int*)alloc((size_t)nbkt * CSR_CAP * 4);
  int2* rowdeg     = (int2*)alloc((size_t)N * 8);
  unsigned short* t_in  = (unsigned short*)alloc(32768 * 2);
  unsigned short* t_l1  = (unsigned short*)alloc(16384 * 2);
  unsigned short* t_r1  = (unsigned short*)alloc(16384 * 2);
  unsigned short* t_l2  = (unsigned short*)alloc(16384 * 2);
  unsigned short* t_r2  = (unsigned short*)alloc(16384 * 2);
  unsigned short* t_out = (unsigned short*)alloc(8192 * 2);
  (void)ws_size;

  // ---- CSR build: bucket -> in-LDS counting sort (16B-aligned rows) ----
  hipMemsetAsync(bcur, 0, (size_t)nbkt * 4, stream);
  bucket_fill<<<(E + FILL_EPB - 1) / FILL_EPB, FILL_TPB, 0, stream>>>(
      src, dst, bcur, bedges, nbkt, E);
  bucket_sort<<<nbkt, 256, 0, stream>>>(bcur, bedges, csr, rowdeg, N);
  prep_w<<<(106496 + 255) / 256, 256, 0, stream>>>(
      w_in, w_l1, w_r1, w_l2, w_r2, w_out, t_in, t_l1, t_r1, t_l2, t_r2, t_out);

  int gblocks = (N + 63) / 64;   // 1563
  int ablocks = (N + 15) / 16;   // 6250 (4 nodes per wave, 4 waves per block)

  // h0 = relu(x @ w_in + b_in)       [fp32 A, K=256 via 2 phases of same x]
  gemm_mfma<2, 128, 256, 256, 128, EPI_RELU, true, false><<<gblocks, 256, 0, stream>>>(
      x, x, t_in, t_in, b_in, nullptr, nullptr, buf0, N);
  // mean1
  agg_kernel<<<ablocks, 256, 0, stream>>>((const unsigned*)buf0, rowdeg,
                                          csr, (unsigned*)buf1, N);
  // h1 = relu(bn(mean1@w_l1 + h0@w_r1 + b_l1))
  gemm_mfma<2, 0, 128, 128, 128, EPI_BN, false, false><<<gblocks, 256, 0, stream>>>(
      buf1, buf0, t_l1, t_r1, b_l1, g1, be1, buf2, N);
  // mean2
  agg_kernel<<<ablocks, 256, 0, stream>>>((const unsigned*)buf2, rowdeg,
                                          csr, (unsigned*)buf0, N);
  // h2 = relu(bn(mean2@w_l2 + h1@w_r2 + b_l2))
  gemm_mfma<2, 0, 128, 128, 128, EPI_BN, false, false><<<gblocks, 256, 0, stream>>>(
      buf0, buf2, t_l2, t_r2, b_l2, g2, be2, buf1, N);
  // out = h2 @ w_out + b_out
  gemm_mfma<1, 0, 128, 128, 64, EPI_NONE, false, true><<<gblocks, 256, 0, stream>>>(
      buf1, buf1, t_out, t_out, b_out, nullptr, nullptr, out, N);
}